// Round 4
// baseline (223.350 us; speedup 1.0000x reference)
//
#include <hip/hip_runtime.h>

// ---------------- problem constants ----------------
#define D_MODEL   1024
#define N_HEADS   16
#define D_LATENT  256
#define HEAD_DIM  64
#define SEQ_T     4096
#define BATCH     4
#define M_TOK     (BATCH * SEQ_T)   // 16384

typedef __attribute__((ext_vector_type(8))) short          short8;
typedef __attribute__((ext_vector_type(4))) float          f32x4;
typedef __attribute__((ext_vector_type(8))) unsigned short u16x8;

static __device__ __forceinline__ float b2f(unsigned short u) {
  unsigned x = ((unsigned)u) << 16;
  float f;
  __builtin_memcpy(&f, &x, 4);
  return f;
}
static __device__ __forceinline__ unsigned short f2b(float f) {
  unsigned x;
  __builtin_memcpy(&x, &f, 4);
  x += 0x7fffu + ((x >> 16) & 1u);   // round-to-nearest-even
  return (unsigned short)(x >> 16);
}

static __device__ __forceinline__ void gload_lds16(const unsigned short* g, unsigned short* l) {
  __builtin_amdgcn_global_load_lds(
      (const __attribute__((address_space(1))) unsigned int*)g,
      (__attribute__((address_space(3))) unsigned int*)l, 16, 0, 0);
}

#define PH_BARRIER() __builtin_amdgcn_s_barrier()
#define LGKM0()                                            \
  do {                                                     \
    asm volatile("s_waitcnt lgkmcnt(0)" ::: "memory");     \
    __builtin_amdgcn_sched_barrier(0);                     \
  } while (0)

// ---------------- RoPE cos/sin table: [t][j] j<32, float2{cos,sin} ----------------
__global__ void rope_tab_kernel(float2* __restrict__ tab) {
  int idx = blockIdx.x * blockDim.x + threadIdx.x;
  if (idx >= SEQ_T * 32) return;
  int t = idx >> 5, j = idx & 31;
  float invf = powf(10000.f, -(float)j * (1.f / 32.f));
  float ang = (float)t * invf;
  float s, c;
  sincosf(ang, &s, &c);
  tab[idx] = make_float2(c, s);
}

// ---------------- f32 -> bf16 convert (8 elems/thread) ----------------
__global__ void cvt_kernel(const float* __restrict__ src, unsigned short* __restrict__ dst, int n8) {
  int i = blockIdx.x * blockDim.x + threadIdx.x;
  if (i >= n8) return;
  const float4* s = (const float4*)(src + (size_t)i * 8);
  float4 a = s[0], b = s[1];
  u16x8 o;
  o[0] = f2b(a.x); o[1] = f2b(a.y); o[2] = f2b(a.z); o[3] = f2b(a.w);
  o[4] = f2b(b.x); o[5] = f2b(b.y); o[6] = f2b(b.z); o[7] = f2b(b.w);
  *(u16x8*)(dst + (size_t)i * 8) = o;
}

// ---------------- transpose + convert: src f32 KxN -> dst bf16 NxK ----------------
__global__ __launch_bounds__(256) void tconv_kernel(const float* __restrict__ src,
                                                    unsigned short* __restrict__ dst,
                                                    int K, int N) {
  __shared__ float tile[32][33];
  const int tx = threadIdx.x & 31, ty = threadIdx.x >> 5;  // ty 0..7
  const int nb = blockIdx.x * 32, kb = blockIdx.y * 32;
#pragma unroll
  for (int j = 0; j < 4; ++j)
    tile[ty + 8 * j][tx] = src[(size_t)(kb + ty + 8 * j) * N + nb + tx];
  __syncthreads();
#pragma unroll
  for (int j = 0; j < 4; ++j)
    dst[(size_t)(nb + ty + 8 * j) * K + kb + tx] = f2b(tile[tx][ty + 8 * j]);
}

// =====================================================================
// gemm8p: C(MxN) = A(MxK,bf16) * Bt(NxK,bf16)^T + bias  — m201-style 8-phase.
// BM=BN=256, BK=64, 8 waves (2M x 4N), per-wave C 128x64 (8m x 4n frags).
// LDS: double buffer, A/B tiles 256x64 bf16 each => 128 KiB.
// Per K-tile: 4 phases x {ds_read subtile | issue prefetch | barrier |
//   lgkmcnt(0)+sched_barrier | setprio(1) 16 MFMA setprio(0) | barrier}.
// Prefetch 2 K-tiles ahead into buf[t&1] (the buffer being read):
//   B(t+2) issued at ph2 (B-halves fully consumed by end-ph1),
//   A(t+2) issued at ph3 (A-halves fully consumed by end-ph2).
// ONE vmcnt(8) per K-tile at ph3 (before its barrier): per-wave, guarantees
// tile t+1's 8 loads landed for every thread before the barrier releases.
// Swizzle identical to proven gemm_bt (128B rows, byte ^= (row&7)<<4),
// pre-swizzled global source + swizzled ds_read (rule #21).
// EPI: 1 = RoPE all heads (Q); 2 = RoPE even 64-col blocks (K of KV); 3 = f32 out
// =====================================================================
template <int EPI>
__global__ __launch_bounds__(512, 2) void gemm8p(const unsigned short* __restrict__ A,
                                                 const unsigned short* __restrict__ Bt,
                                                 const float* __restrict__ bias,
                                                 void* __restrict__ Cout,
                                                 const float2* __restrict__ tab,
                                                 int M, int N, int K) {
  __shared__ unsigned short As[2][256 * 64];   // 32 KiB per buffer
  __shared__ unsigned short Bs[2][256 * 64];
  const int tid = threadIdx.x;
  const int lane = tid & 63;
  const int wid = tid >> 6;        // 0..7
  const int wm = wid >> 2;         // 0..1  (M half)
  const int wn = wid & 3;          // 0..3  (N quarter)
  const int l15 = lane & 15, kg = lane >> 4;

  // T1 bijective XCD swizzle (gridDim.x % 8 == 0 for all our launches)
  const int gx = N >> 8;
  const int q8 = (int)gridDim.x >> 3;
  const int bid = (int)blockIdx.x;
  const int sid = (bid & 7) * q8 + (bid >> 3);
  const long mBase = (long)(sid / gx) * 256;
  const long nBase = (long)(sid % gx) * 256;

  const int nt = K >> 6;           // K-tiles of 64

  // staging: per K-tile per thread: 4 gloads A + 4 gloads B (16B each).
  // dest flat byte f = j*8192 + tid*16 ; row = j*64 + (tid>>3) ; col = (tid&7)*16
  const int r0 = tid >> 3;                                  // 0..63
  const int sc = ((tid & 7) * 16) ^ ((r0 & 7) << 4);        // pre-swizzled src byte
  const unsigned short* gA = A + (size_t)(mBase + r0) * K + (sc >> 1);
  const unsigned short* gB = Bt + (size_t)(nBase + r0) * K + (sc >> 1);
  const int dst0 = tid << 4;                                // dest byte base

  // issue order per tile: B (4) then A (4)  -> 8 loads per tile, FIFO by tile
  auto stageB = [&](int t, int buf) {
#pragma unroll
    for (int j = 0; j < 4; ++j)
      gload_lds16(gB + (size_t)j * 64 * K + (size_t)t * 64,
                  (unsigned short*)((char*)&Bs[buf][0] + j * 8192 + dst0));
  };
  auto stageA = [&](int t, int buf) {
#pragma unroll
    for (int j = 0; j < 4; ++j)
      gload_lds16(gA + (size_t)j * 64 * K + (size_t)t * 64,
                  (unsigned short*)((char*)&As[buf][0] + j * 8192 + dst0));
  };

  f32x4 acc[8][4];
#pragma unroll
  for (int m = 0; m < 8; ++m)
#pragma unroll
    for (int n = 0; n < 4; ++n) {
      acc[m][n][0] = 0.f; acc[m][n][1] = 0.f; acc[m][n][2] = 0.f; acc[m][n][3] = 0.f;
    }

  // prologue: tile0 -> buf0, tile1 -> buf1 ; wait tile0 (8 newest outstanding ok)
  stageB(0, 0); stageA(0, 0);
  stageB(1, 1); stageA(1, 1);
  asm volatile("s_waitcnt vmcnt(8)" ::: "memory");
  PH_BARRIER();

  for (int t = 0; t < nt; ++t) {
    const int cur = t & 1;
    const char* sa = (const char*)&As[cur][0];
    const char* sb = (const char*)&Bs[cur][0];
    short8 a[4][2], b[4][2];

    // ---- phase 0: read a(m0-3), b(n0-1) ; MFMA (m0-3)x(n0-1) ----
#pragma unroll
    for (int m = 0; m < 4; ++m) {
      const int row = wm * 128 + m * 16 + l15, sw = (row & 7) << 4;
      a[m][0] = *(const short8*)(sa + row * 128 + ((kg * 16) ^ sw));
      a[m][1] = *(const short8*)(sa + row * 128 + ((64 + kg * 16) ^ sw));
    }
#pragma unroll
    for (int n = 0; n < 2; ++n) {
      const int row = wn * 64 + n * 16 + l15, sw = (row & 7) << 4;
      b[n][0] = *(const short8*)(sb + row * 128 + ((kg * 16) ^ sw));
      b[n][1] = *(const short8*)(sb + row * 128 + ((64 + kg * 16) ^ sw));
    }
    PH_BARRIER(); LGKM0();
    __builtin_amdgcn_s_setprio(1);
#pragma unroll
    for (int m = 0; m < 4; ++m)
#pragma unroll
      for (int n = 0; n < 2; ++n) {
        acc[m][n] = __builtin_amdgcn_mfma_f32_16x16x32_bf16(a[m][0], b[n][0], acc[m][n], 0, 0, 0);
        acc[m][n] = __builtin_amdgcn_mfma_f32_16x16x32_bf16(a[m][1], b[n][1], acc[m][n], 0, 0, 0);
      }
    __builtin_amdgcn_s_setprio(0);
    PH_BARRIER();

    // ---- phase 1: read b(n2-3) ; MFMA (m0-3)x(n2-3) ----
#pragma unroll
    for (int n = 2; n < 4; ++n) {
      const int row = wn * 64 + n * 16 + l15, sw = (row & 7) << 4;
      b[n][0] = *(const short8*)(sb + row * 128 + ((kg * 16) ^ sw));
      b[n][1] = *(const short8*)(sb + row * 128 + ((64 + kg * 16) ^ sw));
    }
    PH_BARRIER(); LGKM0();
    __builtin_amdgcn_s_setprio(1);
#pragma unroll
    for (int m = 0; m < 4; ++m)
#pragma unroll
      for (int n = 2; n < 4; ++n) {
        acc[m][n] = __builtin_amdgcn_mfma_f32_16x16x32_bf16(a[m][0], b[n][0], acc[m][n], 0, 0, 0);
        acc[m][n] = __builtin_amdgcn_mfma_f32_16x16x32_bf16(a[m][1], b[n][1], acc[m][n], 0, 0, 0);
      }
    __builtin_amdgcn_s_setprio(0);
    PH_BARRIER();

    // ---- phase 2: read a(m4-7) ; issue B(t+2) ; MFMA (m4-7)x(n2-3) ----
#pragma unroll
    for (int m = 0; m < 4; ++m) {
      const int row = wm * 128 + (m + 4) * 16 + l15, sw = (row & 7) << 4;
      a[m][0] = *(const short8*)(sa + row * 128 + ((kg * 16) ^ sw));
      a[m][1] = *(const short8*)(sa + row * 128 + ((64 + kg * 16) ^ sw));
    }
    if (t + 2 < nt) stageB(t + 2, cur);   // B-halves of buf[cur] fully read by end-ph1
    PH_BARRIER(); LGKM0();
    __builtin_amdgcn_s_setprio(1);
#pragma unroll
    for (int m = 0; m < 4; ++m)
#pragma unroll
      for (int n = 2; n < 4; ++n) {
        acc[m + 4][n] = __builtin_amdgcn_mfma_f32_16x16x32_bf16(a[m][0], b[n][0], acc[m + 4][n], 0, 0, 0);
        acc[m + 4][n] = __builtin_amdgcn_mfma_f32_16x16x32_bf16(a[m][1], b[n][1], acc[m + 4][n], 0, 0, 0);
      }
    __builtin_amdgcn_s_setprio(0);
    PH_BARRIER();

    // ---- phase 3: issue A(t+2) ; vmcnt ; MFMA (m4-7)x(n0-1) ----
    if (t + 2 < nt) {
      stageA(t + 2, cur);                 // A-halves of buf[cur] fully read by end-ph2
      asm volatile("s_waitcnt vmcnt(8)" ::: "memory");   // tile t+1 landed (per wave)
    } else {
      asm volatile("s_waitcnt vmcnt(0)" ::: "memory");   // drain tail
    }
    PH_BARRIER();
    __builtin_amdgcn_s_setprio(1);
#pragma unroll
    for (int m = 0; m < 4; ++m)
#pragma unroll
      for (int n = 0; n < 2; ++n) {
        acc[m + 4][n] = __builtin_amdgcn_mfma_f32_16x16x32_bf16(a[m][0], b[n][0], acc[m + 4][n], 0, 0, 0);
        acc[m + 4][n] = __builtin_amdgcn_mfma_f32_16x16x32_bf16(a[m][1], b[n][1], acc[m + 4][n], 0, 0, 0);
      }
    __builtin_amdgcn_s_setprio(0);
    PH_BARRIER();
  }

  // ---------------- epilogue ----------------
  const long rowB = mBase + (long)wm * 128;
  const int colB = (int)nBase + wn * 64;
  const bool doRope = (EPI == 1) || (EPI == 2 && (((colB >> 6) & 1) == 0));

  if (!doRope) {
#pragma unroll
    for (int n = 0; n < 4; ++n) {
      const int col = colB + n * 16 + l15;
      const float bb = bias[col];
#pragma unroll
      for (int m = 0; m < 8; ++m) {
#pragma unroll
        for (int i = 0; i < 4; ++i) {
          const long row = rowB + m * 16 + kg * 4 + i;
          const float v = acc[m][n][i] + bb;
          if (EPI == 3)
            ((float*)Cout)[row * N + col] = v;
          else
            ((unsigned short*)Cout)[row * N + col] = f2b(v);
        }
      }
    }
  } else {
#pragma unroll
    for (int p = 0; p < 2; ++p) {
      const int c1 = colB + p * 16 + l15;
      const int c2 = c1 + 32;
      const float b1 = bias[c1], b2 = bias[c2];
      const int j = p * 16 + l15;  // freq index 0..31
#pragma unroll
      for (int m = 0; m < 8; ++m) {
#pragma unroll
        for (int i = 0; i < 4; ++i) {
          const long row = rowB + m * 16 + kg * 4 + i;
          const int tt = (int)(row & (SEQ_T - 1));
          const float2 cs = tab[tt * 32 + j];
          const float x1 = acc[m][p][i] + b1;
          const float x2 = acc[m][p + 2][i] + b2;
          ((unsigned short*)Cout)[row * N + c1] = f2b(x1 * cs.x - x2 * cs.y);
          ((unsigned short*)Cout)[row * N + c2] = f2b(x1 * cs.y + x2 * cs.x);
        }
      }
    }
  }
}

// ---------------- old 128x128 GEMM (kept for the small latent GEMM) ----------------
template <int EPI>
__global__ __launch_bounds__(256) void gemm_bt(const unsigned short* __restrict__ A,
                                               const unsigned short* __restrict__ Bt,
                                               const float* __restrict__ bias,
                                               void* __restrict__ Cout,
                                               const float2* __restrict__ tab,
                                               int M, int N, int K) {
  __shared__ unsigned short As[128 * 64];
  __shared__ unsigned short Bs[128 * 64];
  const int tid = threadIdx.x;
  const int lane = tid & 63;
  const int wid = tid >> 6;
  const int wr = wid >> 1, wc = wid & 1;
  const int l15 = lane & 15, kg = lane >> 4;

  const int gx = N >> 7;
  const int nwg = gridDim.x;
  const int q8 = nwg >> 3;
  const int bid = blockIdx.x;
  const int sid = (bid & 7) * q8 + (bid >> 3);
  const int bx = sid % gx;
  const int by = sid / gx;
  const long mBase = (long)by * 128;
  const long nBase = (long)bx * 128;

  f32x4 acc[4][4];
#pragma unroll
  for (int m = 0; m < 4; ++m)
#pragma unroll
    for (int n = 0; n < 4; ++n) {
      acc[m][n][0] = 0.f; acc[m][n][1] = 0.f; acc[m][n][2] = 0.f; acc[m][n][3] = 0.f;
    }

  for (int kt = 0; kt < K; kt += 64) {
#pragma unroll
    for (int i = 0; i < 4; ++i) {
      const int flatB = i * 4096 + tid * 16;
      const int row = flatB >> 7;
      const int kb = (flatB & 127) ^ ((row & 7) << 4);
      gload_lds16(A + (size_t)(mBase + row) * K + kt + (kb >> 1),
                  (unsigned short*)((char*)As + flatB));
      gload_lds16(Bt + (size_t)(nBase + row) * K + kt + (kb >> 1),
                  (unsigned short*)((char*)Bs + flatB));
    }
    __syncthreads();
#pragma unroll
    for (int ks = 0; ks < 2; ++ks) {
      short8 af[4], bfr[4];
      const int koff = ks * 64 + kg * 16;
#pragma unroll
      for (int m = 0; m < 4; ++m) {
        const int row = wr * 64 + m * 16 + l15;
        af[m] = *(const short8*)((const char*)As + row * 128 + (koff ^ ((row & 7) << 4)));
      }
#pragma unroll
      for (int n = 0; n < 4; ++n) {
        const int row = wc * 64 + n * 16 + l15;
        bfr[n] = *(const short8*)((const char*)Bs + row * 128 + (koff ^ ((row & 7) << 4)));
      }
#pragma unroll
      for (int m = 0; m < 4; ++m)
#pragma unroll
        for (int n = 0; n < 4; ++n)
          acc[m][n] = __builtin_amdgcn_mfma_f32_16x16x32_bf16(af[m], bfr[n], acc[m][n], 0, 0, 0);
    }
    __syncthreads();
  }

  const int colB = (int)nBase + wc * 64;
  const long rowB = mBase + (long)wr * 64;
#pragma unroll
  for (int n = 0; n < 4; ++n) {
    const int col = colB + n * 16 + l15;
    const float bb = bias[col];
#pragma unroll
    for (int m = 0; m < 4; ++m) {
#pragma unroll
      for (int i = 0; i < 4; ++i) {
        const long row = rowB + m * 16 + kg * 4 + i;
        const float v = acc[m][n][i] + bb;
        ((unsigned short*)Cout)[row * N + col] = f2b(v);
      }
    }
  }
  (void)tab; (void)M;
}

// ---------------- per-token head-vs-head attention ----------------
__global__ __launch_bounds__(256) void attn_kernel(const unsigned short* __restrict__ Qb,
                                                   const unsigned short* __restrict__ KVb,
                                                   unsigned short* __restrict__ Ab) {
  __shared__ float sm[4 * 3 * 16 * 68];
  const int tid = threadIdx.x;
  const int w = tid >> 6, lane = tid & 63;
  const long token = (long)blockIdx.x * 4 + w;
  float* qs = &sm[w * (3 * 16 * 68)];
  float* ks = qs + 16 * 68;
  float* vs = ks + 16 * 68;

  {
    const u16x8* qg = (const u16x8*)(Qb + token * 1024 + lane * 16);
    u16x8 a0 = qg[0], a1 = qg[1];
    const int h = lane >> 2, d0 = (lane & 3) * 16;
    float tmp[16];
#pragma unroll
    for (int j = 0; j < 8; ++j) { tmp[j] = b2f(a0[j]); tmp[8 + j] = b2f(a1[j]); }
    float4* dst = (float4*)&qs[h * 68 + d0];
#pragma unroll
    for (int v = 0; v < 4; ++v) dst[v] = *(float4*)&tmp[4 * v];
  }
  {
    const u16x8* kg = (const u16x8*)(KVb + token * 2048 + lane * 32);
    u16x8 c0 = kg[0], c1 = kg[1], c2 = kg[2], c3 = kg[3];
    const int h = lane >> 2, part = lane & 3;
    float tmp[32];
#pragma unroll
    for (int j = 0; j < 8; ++j) {
      tmp[j] = b2f(c0[j]); tmp[8 + j] = b2f(c1[j]);
      tmp[16 + j] = b2f(c2[j]); tmp[24 + j] = b2f(c3[j]);
    }
    float* dst = (part < 2) ? &ks[h * 68 + part * 32] : &vs[h * 68 + (part - 2) * 32];
    float4* d4 = (float4*)dst;
#pragma unroll
    for (int v = 0; v < 8; ++v) d4[v] = *(float4*)&tmp[4 * v];
  }
  __syncthreads();

  const int h = lane >> 2, b = lane & 3;
  float s[4];
#pragma unroll
  for (int a = 0; a < 4; ++a) {
    const int g = 4 * a + b;
    const float4* qr = (const float4*)&qs[h * 68];
    const float4* kr = (const float4*)&ks[g * 68];
    float accv = 0.f;
#pragma unroll
    for (int t = 0; t < 16; ++t) {
      float4 qv = qr[t], kv = kr[t];
      accv += qv.x * kv.x + qv.y * kv.y + qv.z * kv.z + qv.w * kv.w;
    }
    s[a] = accv * 0.125f;
  }
  float mx = fmaxf(fmaxf(s[0], s[1]), fmaxf(s[2], s[3]));
  mx = fmaxf(mx, __shfl_xor(mx, 1, 64));
  mx = fmaxf(mx, __shfl_xor(mx, 2, 64));
  float e[4], sum = 0.f;
#pragma unroll
  for (int a = 0; a < 4; ++a) { e[a] = __expf(s[a] - mx); sum += e[a]; }
  sum += __shfl_xor(sum, 1, 64);
  sum += __shfl_xor(sum, 2, 64);
  const float rinv = 1.f / sum;
  float p[4];
#pragma unroll
  for (int a = 0; a < 4; ++a) p[a] = e[a] * rinv;

  float pf[16];
  const int qbase = lane & ~3;
#pragma unroll
  for (int bb = 0; bb < 4; ++bb)
#pragma unroll
    for (int a = 0; a < 4; ++a) pf[4 * a + bb] = __shfl(p[a], qbase + bb, 64);

#pragma unroll
  for (int k16 = 0; k16 < 16; ++k16) {
    const int d = b + 4 * k16;
    float o = 0.f;
#pragma unroll
    for (int g = 0; g < 16; ++g) o += pf[g] * vs[g * 68 + d];
    Ab[token * 1024 + h * 64 + d] = f2b(o);
  }
}

// ---------------- workspace layout (bytes) ----------------
#define OFF_TAB  0UL
#define OFF_XB   1048576UL
#define OFF_WQT  34603008UL
#define OFF_WDT  36700160UL
#define OFF_WUT  37224448UL
#define OFF_WOT  38273024UL
#define OFF_QB   40370176UL
#define OFF_LB   73924608UL
#define OFF_KVB  82313216UL
#define WS_NEEDED 149422080UL
#define OFF_AB   OFF_XB   // X dead after latent GEMM; attention output reuses it

extern "C" void kernel_launch(void* const* d_in, const int* in_sizes, int n_in,
                              void* d_out, int out_size, void* d_ws, size_t ws_size,
                              hipStream_t stream) {
  (void)in_sizes; (void)n_in; (void)out_size;
  if (ws_size < WS_NEEDED) return;

  const float* x     = (const float*)d_in[0];
  const float* Wq    = (const float*)d_in[1];
  const float* bq    = (const float*)d_in[2];
  const float* Wdown = (const float*)d_in[3];
  const float* bdown = (const float*)d_in[4];
  const float* Wup   = (const float*)d_in[5];
  const float* bup   = (const float*)d_in[6];
  const float* Wout  = (const float*)d_in[7];
  const float* bout  = (const float*)d_in[8];

  char* ws = (char*)d_ws;
  float2*         tab = (float2*)(ws + OFF_TAB);
  unsigned short* Xb  = (unsigned short*)(ws + OFF_XB);
  unsigned short* WqT = (unsigned short*)(ws + OFF_WQT);
  unsigned short* WdT = (unsigned short*)(ws + OFF_WDT);
  unsigned short* WuT = (unsigned short*)(ws + OFF_WUT);
  unsigned short* WoT = (unsigned short*)(ws + OFF_WOT);
  unsigned short* Qb  = (unsigned short*)(ws + OFF_QB);
  unsigned short* Lb  = (unsigned short*)(ws + OFF_LB);
  unsigned short* KVb = (unsigned short*)(ws + OFF_KVB);
  unsigned short* Ab  = (unsigned short*)(ws + OFF_AB);

  rope_tab_kernel<<<(SEQ_T * 32 + 255) / 256, 256, 0, stream>>>(tab);
  cvt_kernel<<<(M_TOK * D_MODEL / 8 + 255) / 256, 256, 0, stream>>>(x, Xb, M_TOK * D_MODEL / 8);
  tconv_kernel<<<dim3(D_MODEL / 32, D_MODEL / 32), 256, 0, stream>>>(Wq, WqT, D_MODEL, D_MODEL);
  tconv_kernel<<<dim3(D_LATENT / 32, D_MODEL / 32), 256, 0, stream>>>(Wdown, WdT, D_MODEL, D_LATENT);
  tconv_kernel<<<dim3(2 * D_MODEL / 32, D_LATENT / 32), 256, 0, stream>>>(Wup, WuT, D_LATENT, 2 * D_MODEL);
  tconv_kernel<<<dim3(D_MODEL / 32, D_MODEL / 32), 256, 0, stream>>>(Wout, WoT, D_MODEL, D_MODEL);

  // Q = X*Wq + bq, RoPE fused (EPI 1): 256 blocks, 1/CU
  gemm8p<1><<<(M_TOK / 256) * (D_MODEL / 256), 512, 0, stream>>>(
      Xb, WqT, bq, (void*)Qb, tab, M_TOK, D_MODEL, D_MODEL);
  // latent = X*Wdown + bdown: small GEMM stays on 128^2 kernel (256 blocks)
  gemm_bt<0><<<(D_LATENT / 128) * (M_TOK / 128), 256, 0, stream>>>(
      Xb, WdT, bdown, (void*)Lb, tab, M_TOK, D_LATENT, D_MODEL);
  // KV = latent*Wup + bup, RoPE on k-halves (EPI 2): 512 blocks
  gemm8p<2><<<(M_TOK / 256) * (2 * D_MODEL / 256), 512, 0, stream>>>(
      Lb, WuT, bup, (void*)KVb, tab, M_TOK, 2 * D_MODEL, D_LATENT);
  // attention
  attn_kernel<<<M_TOK / 4, 256, 0, stream>>>(Qb, KVb, Ab);
  // out = att*Wout + bout, f32 (EPI 3): 256 blocks
  gemm8p<3><<<(M_TOK / 256) * (D_MODEL / 256), 512, 0, stream>>>(
      Ab, WoT, bout, d_out, tab, M_TOK, D_MODEL, D_MODEL);
}

// Round 5
// 219.537 us; speedup vs baseline: 1.0174x; 1.0174x over previous
//
#include <hip/hip_runtime.h>

// ---------------- problem constants ----------------
#define D_MODEL   1024
#define N_HEADS   16
#define D_LATENT  256
#define HEAD_DIM  64
#define SEQ_T     4096
#define BATCH     4
#define M_TOK     (BATCH * SEQ_T)   // 16384

typedef __attribute__((ext_vector_type(8))) short          short8;
typedef __attribute__((ext_vector_type(4))) float          f32x4;
typedef __attribute__((ext_vector_type(8))) unsigned short u16x8;

static __device__ __forceinline__ float b2f(unsigned short u) {
  unsigned x = ((unsigned)u) << 16;
  float f;
  __builtin_memcpy(&f, &x, 4);
  return f;
}
static __device__ __forceinline__ unsigned short f2b(float f) {
  unsigned x;
  __builtin_memcpy(&x, &f, 4);
  x += 0x7fffu + ((x >> 16) & 1u);   // round-to-nearest-even
  return (unsigned short)(x >> 16);
}

static __device__ __forceinline__ void gload_lds16(const unsigned short* g, unsigned short* l) {
  __builtin_amdgcn_global_load_lds(
      (const __attribute__((address_space(1))) unsigned int*)g,
      (__attribute__((address_space(3))) unsigned int*)l, 16, 0, 0);
}

#define BAR()    __builtin_amdgcn_s_barrier()
#define LGKM0()  asm volatile("s_waitcnt lgkmcnt(0)" ::: "memory")
#define LGKM8()  asm volatile("s_waitcnt lgkmcnt(8)" ::: "memory")
#define VMCNT6() asm volatile("s_waitcnt vmcnt(6)" ::: "memory")
#define VMCNT0() asm volatile("s_waitcnt vmcnt(0)" ::: "memory")

// ---------------- RoPE cos/sin table: [t][j] j<32, float2{cos,sin} ----------------
__global__ void rope_tab_kernel(float2* __restrict__ tab) {
  int idx = blockIdx.x * blockDim.x + threadIdx.x;
  if (idx >= SEQ_T * 32) return;
  int t = idx >> 5, j = idx & 31;
  float invf = powf(10000.f, -(float)j * (1.f / 32.f));
  float ang = (float)t * invf;
  float s, c;
  sincosf(ang, &s, &c);
  tab[idx] = make_float2(c, s);
}

// ---------------- f32 -> bf16 convert (8 elems/thread) ----------------
__global__ void cvt_kernel(const float* __restrict__ src, unsigned short* __restrict__ dst, int n8) {
  int i = blockIdx.x * blockDim.x + threadIdx.x;
  if (i >= n8) return;
  const float4* s = (const float4*)(src + (size_t)i * 8);
  float4 a = s[0], b = s[1];
  u16x8 o;
  o[0] = f2b(a.x); o[1] = f2b(a.y); o[2] = f2b(a.z); o[3] = f2b(a.w);
  o[4] = f2b(b.x); o[5] = f2b(b.y); o[6] = f2b(b.z); o[7] = f2b(b.w);
  *(u16x8*)(dst + (size_t)i * 8) = o;
}

// ---------------- transpose + convert: src f32 KxN -> dst bf16 NxK ----------------
__global__ __launch_bounds__(256) void tconv_kernel(const float* __restrict__ src,
                                                    unsigned short* __restrict__ dst,
                                                    int K, int N) {
  __shared__ float tile[32][33];
  const int tx = threadIdx.x & 31, ty = threadIdx.x >> 5;  // ty 0..7
  const int nb = blockIdx.x * 32, kb = blockIdx.y * 32;
#pragma unroll
  for (int j = 0; j < 4; ++j)
    tile[ty + 8 * j][tx] = src[(size_t)(kb + ty + 8 * j) * N + nb + tx];
  __syncthreads();
#pragma unroll
  for (int j = 0; j < 4; ++j)
    dst[(size_t)(nb + ty + 8 * j) * K + kb + tx] = f2b(tile[tx][ty + 8 * j]);
}

// =====================================================================
// gemm8p (m201-conformant): C(MxN) = A(MxK) * Bt(NxK)^T + bias, bf16 MFMA.
// BM=BN=256, BK=64, 8 waves (2M x 4N), per-wave C 128x64, 128 KiB LDS dbuf.
// Changes vs previous round (conform to the verified m201 template):
//  - NO sched_barrier(0) (m141: order-pinning costs ~40%); bare lgkmcnt asm.
//  - stage exactly ONE 16KB half-tile (2 gloads/thread) per phase:
//      ph0: A1(t+1) -> buf[cur^1]   (A1 of that buf last read at (t-1)-ph2)
//      ph2: B0(t+2) -> buf[cur]     (B0(t) last read at t-ph1)
//      ph3: B1(t+2), A0(t+2) -> buf[cur]  (B1@ph1, A0@ph2)
//  - ONE vmcnt(6) per K-tile at ph3 = 3 half-tiles in flight (m201's N).
//  - lgkmcnt(8) throttle on the 12-ds_read phase (m201 optional rule).
//  - N,K template constants; 2 K-tiles per unrolled loop iteration.
// Swizzle: byte ^= (row&7)<<4 within 128B rows, pre-swizzled global source
// + swizzled ds_read (rule #21); SQ_LDS_BANK_CONFLICT measured 0.
// EPI: 1 = RoPE all heads (Q); 2 = RoPE even 64-col blocks (K of KV); 3 = f32 out
// =====================================================================
template <int EPI, int NN, int KK>
__global__ __launch_bounds__(512) void gemm8p(const unsigned short* __restrict__ A,
                                              const unsigned short* __restrict__ Bt,
                                              const float* __restrict__ bias,
                                              void* __restrict__ Cout,
                                              const float2* __restrict__ tab) {
  __shared__ unsigned short As[2][16384];   // 32 KiB per buffer
  __shared__ unsigned short Bs[2][16384];
  const int tid = threadIdx.x;
  const int lane = tid & 63;
  const int wid = tid >> 6;        // 0..7
  const int wm = wid >> 2;         // 0..1  (M half)
  const int wn = wid & 3;          // 0..3  (N quarter)
  const int l15 = lane & 15, kg = lane >> 4;

  // T1 bijective XCD swizzle (gridDim.x % 8 == 0 for all our launches)
  constexpr int gx = NN >> 8;
  const int q8 = (int)gridDim.x >> 3;
  const int bid = (int)blockIdx.x;
  const int sid = (bid & 7) * q8 + (bid >> 3);
  const long mBase = (long)(sid / gx) * 256;
  const long nBase = (long)(sid % gx) * 256;

  constexpr int nt = KK >> 6;      // K-tiles of 64 (even, >=4 for our shapes)

  // ---- staging geometry: half-tile = 128 rows x 128 B = 16 KB = 2 gloads/thread
  const int r0 = tid >> 3;                         // row within 64-row j-block
  const int cb = (tid & 7) * 16;                   // col byte within 128B row
  const int scb = cb ^ ((r0 & 7) << 4);            // pre-swizzled source col byte
  const unsigned short* gA = A + (mBase + r0) * KK + (scb >> 1);
  const unsigned short* gB = Bt + (nBase + r0) * KK + (scb >> 1);
  const int dOff = tid << 3;                       // dest elem offset within j-block

  auto stA = [&](int h, int t, int buf) __attribute__((always_inline)) {
#pragma unroll
    for (int j = 0; j < 2; ++j)
      gload_lds16(gA + (size_t)(h * 128 + j * 64) * KK + t * 64,
                  &As[buf][h * 8192 + j * 4096 + dOff]);
  };
  auto stB = [&](int h, int t, int buf) __attribute__((always_inline)) {
#pragma unroll
    for (int j = 0; j < 2; ++j)
      gload_lds16(gB + (size_t)(h * 128 + j * 64) * KK + t * 64,
                  &Bs[buf][h * 8192 + j * 4096 + dOff]);
  };

  f32x4 acc[8][4];
#pragma unroll
  for (int m = 0; m < 8; ++m)
#pragma unroll
    for (int n = 0; n < 4; ++n) {
      acc[m][n][0] = 0.f; acc[m][n][1] = 0.f; acc[m][n][2] = 0.f; acc[m][n][3] = 0.f;
    }

  // ---- prologue: tile0 fully + B0,B1,A0 of tile1 (order matters for vmcnt) ----
  stA(0, 0, 0); stA(1, 0, 0); stB(0, 0, 0); stB(1, 0, 0);
  stB(0, 1, 1); stB(1, 1, 1); stA(0, 1, 1);
  VMCNT6();                      // tile 0 landed; 3 half-tiles of tile 1 in flight
  BAR();

  // ---- K-tile body (cur is a literal at each call site) ----
  auto ktile = [&](int t, int cur) __attribute__((always_inline)) {
    const char* sa = (const char*)&As[cur][0];
    const char* sb = (const char*)&Bs[cur][0];
    short8 a[4][2], b[4][2];

    // phase 0: read a(m0-3), b(n0-1) [12 reads]; stage A1(t+1); MFMA q(m0-3,n0-1)
#pragma unroll
    for (int m = 0; m < 4; ++m) {
      const int row = wm * 128 + m * 16 + l15, sw = (row & 7) << 4;
      a[m][0] = *(const short8*)(sa + row * 128 + ((kg * 16) ^ sw));
      a[m][1] = *(const short8*)(sa + row * 128 + ((64 + kg * 16) ^ sw));
    }
#pragma unroll
    for (int n = 0; n < 2; ++n) {
      const int row = wn * 64 + n * 16 + l15, sw = (row & 7) << 4;
      b[n][0] = *(const short8*)(sb + row * 128 + ((kg * 16) ^ sw));
      b[n][1] = *(const short8*)(sb + row * 128 + ((64 + kg * 16) ^ sw));
    }
    if (t + 1 < nt) stA(1, t + 1, cur ^ 1);
    LGKM8();
    BAR(); LGKM0();
    __builtin_amdgcn_s_setprio(1);
#pragma unroll
    for (int m = 0; m < 4; ++m)
#pragma unroll
      for (int n = 0; n < 2; ++n) {
        acc[m][n] = __builtin_amdgcn_mfma_f32_16x16x32_bf16(a[m][0], b[n][0], acc[m][n], 0, 0, 0);
        acc[m][n] = __builtin_amdgcn_mfma_f32_16x16x32_bf16(a[m][1], b[n][1], acc[m][n], 0, 0, 0);
      }
    __builtin_amdgcn_s_setprio(0);
    BAR();

    // phase 1: read b(n2-3) [4]; MFMA q(m0-3,n2-3)
#pragma unroll
    for (int n = 2; n < 4; ++n) {
      const int row = wn * 64 + n * 16 + l15, sw = (row & 7) << 4;
      b[n][0] = *(const short8*)(sb + row * 128 + ((kg * 16) ^ sw));
      b[n][1] = *(const short8*)(sb + row * 128 + ((64 + kg * 16) ^ sw));
    }
    BAR(); LGKM0();
    __builtin_amdgcn_s_setprio(1);
#pragma unroll
    for (int m = 0; m < 4; ++m)
#pragma unroll
      for (int n = 2; n < 4; ++n) {
        acc[m][n] = __builtin_amdgcn_mfma_f32_16x16x32_bf16(a[m][0], b[n][0], acc[m][n], 0, 0, 0);
        acc[m][n] = __builtin_amdgcn_mfma_f32_16x16x32_bf16(a[m][1], b[n][1], acc[m][n], 0, 0, 0);
      }
    __builtin_amdgcn_s_setprio(0);
    BAR();

    // phase 2: read a(m4-7) [8]; stage B0(t+2); MFMA q(m4-7,n2-3)
#pragma unroll
    for (int m = 0; m < 4; ++m) {
      const int row = wm * 128 + (m + 4) * 16 + l15, sw = (row & 7) << 4;
      a[m][0] = *(const short8*)(sa + row * 128 + ((kg * 16) ^ sw));
      a[m][1] = *(const short8*)(sa + row * 128 + ((64 + kg * 16) ^ sw));
    }
    if (t + 2 < nt) stB(0, t + 2, cur);
    BAR(); LGKM0();
    __builtin_amdgcn_s_setprio(1);
#pragma unroll
    for (int m = 0; m < 4; ++m)
#pragma unroll
      for (int n = 2; n < 4; ++n) {
        acc[m + 4][n] = __builtin_amdgcn_mfma_f32_16x16x32_bf16(a[m][0], b[n][0], acc[m + 4][n], 0, 0, 0);
        acc[m + 4][n] = __builtin_amdgcn_mfma_f32_16x16x32_bf16(a[m][1], b[n][1], acc[m + 4][n], 0, 0, 0);
      }
    __builtin_amdgcn_s_setprio(0);
    BAR();

    // phase 3: stage B1(t+2), A0(t+2); vmcnt(6) once per K-tile; MFMA q(m4-7,n0-1)
    if (t + 2 < nt) {
      stB(1, t + 2, cur);
      stA(0, t + 2, cur);
      VMCNT6();                  // tile t+1 fully landed; t+2's 3 half-tiles in flight
    } else if (t + 1 < nt) {
      VMCNT0();                  // drain tail (only A1(t+1) outstanding)
    }
    BAR();
    __builtin_amdgcn_s_setprio(1);
#pragma unroll
    for (int m = 0; m < 4; ++m)
#pragma unroll
      for (int n = 0; n < 2; ++n) {
        acc[m + 4][n] = __builtin_amdgcn_mfma_f32_16x16x32_bf16(a[m][0], b[n][0], acc[m + 4][n], 0, 0, 0);
        acc[m + 4][n] = __builtin_amdgcn_mfma_f32_16x16x32_bf16(a[m][1], b[n][1], acc[m + 4][n], 0, 0, 0);
      }
    __builtin_amdgcn_s_setprio(0);
    BAR();
  };

#pragma unroll 1
  for (int t = 0; t < nt; t += 2) {
    ktile(t, 0);
    ktile(t + 1, 1);
  }

  // ---------------- epilogue ----------------
  const long rowB = mBase + (long)wm * 128;
  const int colB = (int)nBase + wn * 64;
  const bool doRope = (EPI == 1) || (EPI == 2 && (((colB >> 6) & 1) == 0));

  if (!doRope) {
#pragma unroll
    for (int n = 0; n < 4; ++n) {
      const int col = colB + n * 16 + l15;
      const float bb = bias[col];
#pragma unroll
      for (int m = 0; m < 8; ++m) {
#pragma unroll
        for (int i = 0; i < 4; ++i) {
          const long row = rowB + m * 16 + kg * 4 + i;
          const float v = acc[m][n][i] + bb;
          if (EPI == 3)
            ((float*)Cout)[row * NN + col] = v;
          else
            ((unsigned short*)Cout)[row * NN + col] = f2b(v);
        }
      }
    }
  } else {
#pragma unroll
    for (int p = 0; p < 2; ++p) {
      const int c1 = colB + p * 16 + l15;
      const int c2 = c1 + 32;
      const float b1 = bias[c1], b2 = bias[c2];
      const int j = p * 16 + l15;  // freq index 0..31
#pragma unroll
      for (int m = 0; m < 8; ++m) {
#pragma unroll
        for (int i = 0; i < 4; ++i) {
          const long row = rowB + m * 16 + kg * 4 + i;
          const int tt = (int)(row & (SEQ_T - 1));
          const float2 cs = tab[tt * 32 + j];
          const float x1 = acc[m][p][i] + b1;
          const float x2 = acc[m][p + 2][i] + b2;
          ((unsigned short*)Cout)[row * NN + c1] = f2b(x1 * cs.x - x2 * cs.y);
          ((unsigned short*)Cout)[row * NN + c2] = f2b(x1 * cs.y + x2 * cs.x);
        }
      }
    }
  }
}

// ---------------- old 128x128 GEMM (kept for the small latent GEMM) ----------------
template <int EPI>
__global__ __launch_bounds__(256) void gemm_bt(const unsigned short* __restrict__ A,
                                               const unsigned short* __restrict__ Bt,
                                               const float* __restrict__ bias,
                                               void* __restrict__ Cout,
                                               const float2* __restrict__ tab,
                                               int M, int N, int K) {
  __shared__ unsigned short As[128 * 64];
  __shared__ unsigned short Bs[128 * 64];
  const int tid = threadIdx.x;
  const int lane = tid & 63;
  const int wid = tid >> 6;
  const int wr = wid >> 1, wc = wid & 1;
  const int l15 = lane & 15, kg = lane >> 4;

  const int gx = N >> 7;
  const int nwg = gridDim.x;
  const int q8 = nwg >> 3;
  const int bid = blockIdx.x;
  const int sid = (bid & 7) * q8 + (bid >> 3);
  const int bx = sid % gx;
  const int by = sid / gx;
  const long mBase = (long)by * 128;
  const long nBase = (long)bx * 128;

  f32x4 acc[4][4];
#pragma unroll
  for (int m = 0; m < 4; ++m)
#pragma unroll
    for (int n = 0; n < 4; ++n) {
      acc[m][n][0] = 0.f; acc[m][n][1] = 0.f; acc[m][n][2] = 0.f; acc[m][n][3] = 0.f;
    }

  for (int kt = 0; kt < K; kt += 64) {
#pragma unroll
    for (int i = 0; i < 4; ++i) {
      const int flatB = i * 4096 + tid * 16;
      const int row = flatB >> 7;
      const int kb = (flatB & 127) ^ ((row & 7) << 4);
      gload_lds16(A + (size_t)(mBase + row) * K + kt + (kb >> 1),
                  (unsigned short*)((char*)As + flatB));
      gload_lds16(Bt + (size_t)(nBase + row) * K + kt + (kb >> 1),
                  (unsigned short*)((char*)Bs + flatB));
    }
    __syncthreads();
#pragma unroll
    for (int ks = 0; ks < 2; ++ks) {
      short8 af[4], bfr[4];
      const int koff = ks * 64 + kg * 16;
#pragma unroll
      for (int m = 0; m < 4; ++m) {
        const int row = wr * 64 + m * 16 + l15;
        af[m] = *(const short8*)((const char*)As + row * 128 + (koff ^ ((row & 7) << 4)));
      }
#pragma unroll
      for (int n = 0; n < 4; ++n) {
        const int row = wc * 64 + n * 16 + l15;
        bfr[n] = *(const short8*)((const char*)Bs + row * 128 + (koff ^ ((row & 7) << 4)));
      }
#pragma unroll
      for (int m = 0; m < 4; ++m)
#pragma unroll
        for (int n = 0; n < 4; ++n)
          acc[m][n] = __builtin_amdgcn_mfma_f32_16x16x32_bf16(af[m], bfr[n], acc[m][n], 0, 0, 0);
    }
    __syncthreads();
  }

  const int colB = (int)nBase + wc * 64;
  const long rowB = mBase + (long)wr * 64;
#pragma unroll
  for (int n = 0; n < 4; ++n) {
    const int col = colB + n * 16 + l15;
    const float bb = bias[col];
#pragma unroll
    for (int m = 0; m < 4; ++m) {
#pragma unroll
      for (int i = 0; i < 4; ++i) {
        const long row = rowB + m * 16 + kg * 4 + i;
        const float v = acc[m][n][i] + bb;
        ((unsigned short*)Cout)[row * N + col] = f2b(v);
      }
    }
  }
  (void)tab; (void)M;
}

// ---------------- per-token head-vs-head attention ----------------
__global__ __launch_bounds__(256) void attn_kernel(const unsigned short* __restrict__ Qb,
                                                   const unsigned short* __restrict__ KVb,
                                                   unsigned short* __restrict__ Ab) {
  __shared__ float sm[4 * 3 * 16 * 68];
  const int tid = threadIdx.x;
  const int w = tid >> 6, lane = tid & 63;
  const long token = (long)blockIdx.x * 4 + w;
  float* qs = &sm[w * (3 * 16 * 68)];
  float* ks = qs + 16 * 68;
  float* vs = ks + 16 * 68;

  {
    const u16x8* qg = (const u16x8*)(Qb + token * 1024 + lane * 16);
    u16x8 a0 = qg[0], a1 = qg[1];
    const int h = lane >> 2, d0 = (lane & 3) * 16;
    float tmp[16];
#pragma unroll
    for (int j = 0; j < 8; ++j) { tmp[j] = b2f(a0[j]); tmp[8 + j] = b2f(a1[j]); }
    float4* dst = (float4*)&qs[h * 68 + d0];
#pragma unroll
    for (int v = 0; v < 4; ++v) dst[v] = *(float4*)&tmp[4 * v];
  }
  {
    const u16x8* kg = (const u16x8*)(KVb + token * 2048 + lane * 32);
    u16x8 c0 = kg[0], c1 = kg[1], c2 = kg[2], c3 = kg[3];
    const int h = lane >> 2, part = lane & 3;
    float tmp[32];
#pragma unroll
    for (int j = 0; j < 8; ++j) {
      tmp[j] = b2f(c0[j]); tmp[8 + j] = b2f(c1[j]);
      tmp[16 + j] = b2f(c2[j]); tmp[24 + j] = b2f(c3[j]);
    }
    float* dst = (part < 2) ? &ks[h * 68 + part * 32] : &vs[h * 68 + (part - 2) * 32];
    float4* d4 = (float4*)dst;
#pragma unroll
    for (int v = 0; v < 8; ++v) d4[v] = *(float4*)&tmp[4 * v];
  }
  __syncthreads();

  const int h = lane >> 2, b = lane & 3;
  float s[4];
#pragma unroll
  for (int a = 0; a < 4; ++a) {
    const int g = 4 * a + b;
    const float4* qr = (const float4*)&qs[h * 68];
    const float4* kr = (const float4*)&ks[g * 68];
    float accv = 0.f;
#pragma unroll
    for (int t = 0; t < 16; ++t) {
      float4 qv = qr[t], kv = kr[t];
      accv += qv.x * kv.x + qv.y * kv.y + qv.z * kv.z + qv.w * kv.w;
    }
    s[a] = accv * 0.125f;
  }
  float mx = fmaxf(fmaxf(s[0], s[1]), fmaxf(s[2], s[3]));
  mx = fmaxf(mx, __shfl_xor(mx, 1, 64));
  mx = fmaxf(mx, __shfl_xor(mx, 2, 64));
  float e[4], sum = 0.f;
#pragma unroll
  for (int a = 0; a < 4; ++a) { e[a] = __expf(s[a] - mx); sum += e[a]; }
  sum += __shfl_xor(sum, 1, 64);
  sum += __shfl_xor(sum, 2, 64);
  const float rinv = 1.f / sum;
  float p[4];
#pragma unroll
  for (int a = 0; a < 4; ++a) p[a] = e[a] * rinv;

  float pf[16];
  const int qbase = lane & ~3;
#pragma unroll
  for (int bb = 0; bb < 4; ++bb)
#pragma unroll
    for (int a = 0; a < 4; ++a) pf[4 * a + bb] = __shfl(p[a], qbase + bb, 64);

#pragma unroll
  for (int k16 = 0; k16 < 16; ++k16) {
    const int d = b + 4 * k16;
    float o = 0.f;
#pragma unroll
    for (int g = 0; g < 16; ++g) o += pf[g] * vs[g * 68 + d];
    Ab[token * 1024 + h * 64 + d] = f2b(o);
  }
}

// ---------------- workspace layout (bytes) ----------------
#define OFF_TAB  0UL
#define OFF_XB   1048576UL
#define OFF_WQT  34603008UL
#define OFF_WDT  36700160UL
#define OFF_WUT  37224448UL
#define OFF_WOT  38273024UL
#define OFF_QB   40370176UL
#define OFF_LB   73924608UL
#define OFF_KVB  82313216UL
#define WS_NEEDED 149422080UL
#define OFF_AB   OFF_XB   // X dead after latent GEMM; attention output reuses it

extern "C" void kernel_launch(void* const* d_in, const int* in_sizes, int n_in,
                              void* d_out, int out_size, void* d_ws, size_t ws_size,
                              hipStream_t stream) {
  (void)in_sizes; (void)n_in; (void)out_size;
  if (ws_size < WS_NEEDED) return;

  const float* x     = (const float*)d_in[0];
  const float* Wq    = (const float*)d_in[1];
  const float* bq    = (const float*)d_in[2];
  const float* Wdown = (const float*)d_in[3];
  const float* bdown = (const float*)d_in[4];
  const float* Wup   = (const float*)d_in[5];
  const float* bup   = (const float*)d_in[6];
  const float* Wout  = (const float*)d_in[7];
  const float* bout  = (const float*)d_in[8];

  char* ws = (char*)d_ws;
  float2*         tab = (float2*)(ws + OFF_TAB);
  unsigned short* Xb  = (unsigned short*)(ws + OFF_XB);
  unsigned short* WqT = (unsigned short*)(ws + OFF_WQT);
  unsigned short* WdT = (unsigned short*)(ws + OFF_WDT);
  unsigned short* WuT = (unsigned short*)(ws + OFF_WUT);
  unsigned short* WoT = (unsigned short*)(ws + OFF_WOT);
  unsigned short* Qb  = (unsigned short*)(ws + OFF_QB);
  unsigned short* Lb  = (unsigned short*)(ws + OFF_LB);
  unsigned short* KVb = (unsigned short*)(ws + OFF_KVB);
  unsigned short* Ab  = (unsigned short*)(ws + OFF_AB);

  rope_tab_kernel<<<(SEQ_T * 32 + 255) / 256, 256, 0, stream>>>(tab);
  cvt_kernel<<<(M_TOK * D_MODEL / 8 + 255) / 256, 256, 0, stream>>>(x, Xb, M_TOK * D_MODEL / 8);
  tconv_kernel<<<dim3(D_MODEL / 32, D_MODEL / 32), 256, 0, stream>>>(Wq, WqT, D_MODEL, D_MODEL);
  tconv_kernel<<<dim3(D_LATENT / 32, D_MODEL / 32), 256, 0, stream>>>(Wdown, WdT, D_MODEL, D_LATENT);
  tconv_kernel<<<dim3(2 * D_MODEL / 32, D_LATENT / 32), 256, 0, stream>>>(Wup, WuT, D_LATENT, 2 * D_MODEL);
  tconv_kernel<<<dim3(D_MODEL / 32, D_MODEL / 32), 256, 0, stream>>>(Wout, WoT, D_MODEL, D_MODEL);

  // Q = X*Wq + bq, RoPE fused (EPI 1): 256 blocks, 1/CU
  gemm8p<1, D_MODEL, D_MODEL><<<(M_TOK / 256) * (D_MODEL / 256), 512, 0, stream>>>(
      Xb, WqT, bq, (void*)Qb, tab);
  // latent = X*Wdown + bdown: small GEMM on 128^2 kernel (256 blocks)
  gemm_bt<0><<<(D_LATENT / 128) * (M_TOK / 128), 256, 0, stream>>>(
      Xb, WdT, bdown, (void*)Lb, tab, M_TOK, D_LATENT, D_MODEL);
  // KV = latent*Wup + bup, RoPE on k-halves (EPI 2): 512 blocks
  gemm8p<2, 2 * D_MODEL, D_LATENT><<<(M_TOK / 256) * (2 * D_MODEL / 256), 512, 0, stream>>>(
      Lb, WuT, bup, (void*)KVb, tab);
  // attention
  attn_kernel<<<M_TOK / 4, 256, 0, stream>>>(Qb, KVb, Ab);
  // out = att*Wout + bout, f32 (EPI 3): 256 blocks
  gemm8p<3, D_MODEL, D_MODEL><<<(M_TOK / 256) * (D_MODEL / 256), 512, 0, stream>>>(
      Ab, WoT, bout, d_out, tab);
}